// Round 1
// baseline (841.614 us; speedup 1.0000x reference)
//
#include <hip/hip_runtime.h>
#include <stdint.h>

#define N_NODES  100000
#define N_EDGES  1600000
#define IN_FEATS 128
#define HID      32
#define N_REL    5
#define N_BASES  2
#define N_PAIRS  4096

#define SCAN_BLOCKS 391   // ceil(100000/256)

// ---------------- CSR build ----------------

__global__ void k_hist(const int* __restrict__ dst, int* __restrict__ counts) {
    int e = blockIdx.x * blockDim.x + threadIdx.x;
    if (e < N_EDGES) atomicAdd(&counts[dst[e]], 1);
}

__global__ void k_scan_a(const int* __restrict__ counts, int* __restrict__ excl,
                         int* __restrict__ partials) {
    __shared__ int s[256];
    int i = blockIdx.x * 256 + threadIdx.x;
    int v = (i < N_NODES) ? counts[i] : 0;
    s[threadIdx.x] = v;
    __syncthreads();
    for (int off = 1; off < 256; off <<= 1) {
        int t = (threadIdx.x >= off) ? s[threadIdx.x - off] : 0;
        __syncthreads();
        s[threadIdx.x] += t;
        __syncthreads();
    }
    if (i < N_NODES) excl[i] = s[threadIdx.x] - v;   // exclusive within block
    if (threadIdx.x == 255) partials[blockIdx.x] = s[255];
}

__global__ void k_scan_b(int* __restrict__ partials, int nblk) {
    __shared__ int s[512];
    int t = threadIdx.x;
    int v = (t < nblk) ? partials[t] : 0;
    s[t] = v;
    __syncthreads();
    for (int off = 1; off < 512; off <<= 1) {
        int u = (t >= off) ? s[t - off] : 0;
        __syncthreads();
        s[t] += u;
        __syncthreads();
    }
    if (t < nblk) partials[t] = s[t] - v;            // exclusive
}

__global__ void k_scan_c(int* __restrict__ offsets, int* __restrict__ cursor,
                         const int* __restrict__ partials) {
    int i = blockIdx.x * 256 + threadIdx.x;
    if (i < N_NODES) {
        int v = offsets[i] + partials[blockIdx.x];
        offsets[i] = v;
        cursor[i]  = v;
    }
    if (blockIdx.x == 0 && threadIdx.x == 0) offsets[N_NODES] = N_EDGES;
}

__global__ void k_scatter(const int* __restrict__ src, const int* __restrict__ dst,
                          const int* __restrict__ etype, const float* __restrict__ mask,
                          int* __restrict__ cursor, int2* __restrict__ ebuf) {
    int e = blockIdx.x * blockDim.x + threadIdx.x;
    if (e >= N_EDGES) return;
    int d = dst[e];
    int pos = atomicAdd(&cursor[d], 1);
    int2 pk;
    pk.x = (src[e] << 3) | etype[e];
    pk.y = __float_as_int(mask[e]);
    ebuf[pos] = pk;
}

// ---------------- node transform: xb = x@V (both bases), agg = x@loop + b ----------------

template <int D>
__global__ void k_transform(const float* __restrict__ xin, int xstride,
                            const float* __restrict__ V, const float* __restrict__ loopw,
                            const float* __restrict__ bias,
                            float* __restrict__ xb, float* __restrict__ agg) {
    __shared__ float Wc[D * 96];   // [d][j], j<64: basis cols (b*32+o); j>=64: loop cols
    for (int idx = threadIdx.x; idx < D * 96; idx += blockDim.x) {
        int d = idx / 96, j = idx % 96;
        float w;
        if (j < 64) { int b = j >> 5, o = j & 31; w = V[(b * D + d) * 32 + o]; }
        else        { w = loopw[d * 32 + (j - 64)]; }
        Wc[idx] = w;
    }
    __syncthreads();
    int n = blockIdx.x * blockDim.x + threadIdx.x;
    if (n >= N_NODES) return;
    float acc[96];
#pragma unroll
    for (int j = 0; j < 96; j++) acc[j] = 0.f;
    const float* xr = xin + (size_t)n * xstride;
    for (int d = 0; d < D; d++) {
        float xd = xr[d];
#pragma unroll
        for (int j = 0; j < 96; j++) acc[j] += xd * Wc[d * 96 + j];
    }
    float* xbp = xb + (size_t)n * 64;
#pragma unroll
    for (int j = 0; j < 64; j++) xbp[j] = acc[j];
    float* ap = agg + (size_t)n * 32;
#pragma unroll
    for (int o = 0; o < 32; o++) ap[o] = acc[64 + o] + bias[o];
}

// ---------------- per-node aggregation (no atomics; 32 lanes per node) ----------------

__global__ void k_aggregate(const int* __restrict__ offsets, const int2* __restrict__ ebuf,
                            const float* __restrict__ xb, const float* __restrict__ comp,
                            const float* __restrict__ agg, float* __restrict__ hout,
                            int hstride) {
    __shared__ float scomp[16];
    if (threadIdx.x < N_REL * N_BASES) scomp[threadIdx.x] = comp[threadIdx.x];
    __syncthreads();
    int g = threadIdx.x >> 5;      // 8 node-groups per 256-thread block
    int o = threadIdx.x & 31;
    int v = blockIdx.x * 8 + g;
    if (v >= N_NODES) return;
    int s0 = offsets[v], s1 = offsets[v + 1];
    float acc = agg[(size_t)v * 32 + o];
    for (int e = s0; e < s1; e++) {
        int2 pk = ebuf[e];
        float m = __int_as_float(pk.y);
        int sn = pk.x >> 3, rel = pk.x & 7;
        float c0 = scomp[rel * 2], c1 = scomp[rel * 2 + 1];
        const float* xr = xb + (size_t)sn * 64;
        acc += m * (c0 * xr[o] + c1 * xr[32 + o]);
    }
    hout[(size_t)v * hstride + o] = tanhf(acc);
}

// ---------------- MLP head ----------------

__global__ void k_mlp(const float* __restrict__ concat, const int* __restrict__ uidx,
                      const int* __restrict__ iidx,
                      const float* __restrict__ w1, const float* __restrict__ bw1,
                      const float* __restrict__ w2, const float* __restrict__ bw2,
                      float* __restrict__ out) {
    __shared__ float feats[192];
    __shared__ float red[2];
    int p = blockIdx.x;
    int t = threadIdx.x;   // 128 threads
    int u = uidx[p], it = iidx[p];
    for (int k = t; k < 192; k += 128)
        feats[k] = (k < 96) ? concat[(size_t)u * 96 + k] : concat[(size_t)it * 96 + (k - 96)];
    __syncthreads();
    float acc = bw1[t];
    for (int k = 0; k < 192; k++) acc += feats[k] * w1[k * 128 + t];
    float h = fmaxf(acc, 0.f);
    float part = h * w2[t];
    for (int off = 32; off > 0; off >>= 1) part += __shfl_down(part, off, 64);
    if ((t & 63) == 0) red[t >> 6] = part;
    __syncthreads();
    if (t == 0) out[p] = red[0] + red[1] + bw2[0];
}

// ---------------- launch ----------------

extern "C" void kernel_launch(void* const* d_in, const int* in_sizes, int n_in,
                              void* d_out, int out_size, void* d_ws, size_t ws_size,
                              hipStream_t stream) {
    const float* x         = (const float*)d_in[0];
    const float* edge_mask = (const float*)d_in[1];
    const int*   etype     = (const int*)d_in[2];
    const int*   src       = (const int*)d_in[3];
    const int*   dst       = (const int*)d_in[4];
    const int*   users_idx = (const int*)d_in[5];
    const int*   items_idx = (const int*)d_in[6];
    const float* V1        = (const float*)d_in[7];
    const float* comp1     = (const float*)d_in[8];
    const float* loop1     = (const float*)d_in[9];
    const float* b1        = (const float*)d_in[10];
    const float* V2        = (const float*)d_in[11];
    const float* comp2     = (const float*)d_in[12];
    const float* loop2     = (const float*)d_in[13];
    const float* b2        = (const float*)d_in[14];
    const float* V3        = (const float*)d_in[15];
    const float* comp3     = (const float*)d_in[16];
    const float* loop3     = (const float*)d_in[17];
    const float* b3        = (const float*)d_in[18];
    const float* w1        = (const float*)d_in[19];
    const float* bw1       = (const float*)d_in[20];
    const float* w2        = (const float*)d_in[21];
    const float* bw2       = (const float*)d_in[22];
    float* out = (float*)d_out;

    // workspace carve-up (256B aligned)
    uintptr_t w = (uintptr_t)d_ws;
    auto al = [&](size_t bytes) { uintptr_t p = (w + 255) & ~(uintptr_t)255; w = p + bytes; return p; };
    int*   counts   = (int*)al(sizeof(int) * N_NODES);
    int*   offsets  = (int*)al(sizeof(int) * (N_NODES + 1));
    int*   cursor   = (int*)al(sizeof(int) * N_NODES);
    int*   partials = (int*)al(sizeof(int) * 512);
    int2*  ebuf     = (int2*)al(sizeof(int2) * N_EDGES);
    float* xb       = (float*)al(sizeof(float) * (size_t)N_NODES * 64);
    float* agg      = (float*)al(sizeof(float) * (size_t)N_NODES * 32);
    float* concat   = (float*)al(sizeof(float) * (size_t)N_NODES * 96);

    hipMemsetAsync(counts, 0, sizeof(int) * N_NODES, stream);

    k_hist<<<N_EDGES / 256, 256, 0, stream>>>(dst, counts);
    k_scan_a<<<SCAN_BLOCKS, 256, 0, stream>>>(counts, offsets, partials);
    k_scan_b<<<1, 512, 0, stream>>>(partials, SCAN_BLOCKS);
    k_scan_c<<<SCAN_BLOCKS, 256, 0, stream>>>(offsets, cursor, partials);
    k_scatter<<<N_EDGES / 256, 256, 0, stream>>>(src, dst, etype, edge_mask, cursor, ebuf);

    // layer 1: in = x (stride 128)
    k_transform<IN_FEATS><<<(N_NODES + 127) / 128, 128, 0, stream>>>(x, IN_FEATS, V1, loop1, b1, xb, agg);
    k_aggregate<<<(N_NODES + 7) / 8, 256, 0, stream>>>(offsets, ebuf, xb, comp1, agg, concat + 0, 96);

    // layer 2: in = h1 (concat col 0..31, stride 96)
    k_transform<HID><<<(N_NODES + 127) / 128, 128, 0, stream>>>(concat + 0, 96, V2, loop2, b2, xb, agg);
    k_aggregate<<<(N_NODES + 7) / 8, 256, 0, stream>>>(offsets, ebuf, xb, comp2, agg, concat + 32, 96);

    // layer 3: in = h2 (concat col 32..63, stride 96)
    k_transform<HID><<<(N_NODES + 127) / 128, 128, 0, stream>>>(concat + 32, 96, V3, loop3, b3, xb, agg);
    k_aggregate<<<(N_NODES + 7) / 8, 256, 0, stream>>>(offsets, ebuf, xb, comp3, agg, concat + 64, 96);

    k_mlp<<<N_PAIRS, 128, 0, stream>>>(concat, users_idx, items_idx, w1, bw1, w2, bw2, out);
}

// Round 2
// 746.226 us; speedup vs baseline: 1.1278x; 1.1278x over previous
//
#include <hip/hip_runtime.h>
#include <stdint.h>

#define N_NODES  100000
#define N_EDGES  1600000
#define IN_FEATS 128
#define HID      32
#define N_REL    5
#define N_BASES  2
#define N_PAIRS  4096

#define SCAN_BLOCKS 391   // ceil(100000/256)

// ---------------- CSR build ----------------

__global__ void k_hist(const int* __restrict__ dst, int* __restrict__ counts) {
    int e = blockIdx.x * blockDim.x + threadIdx.x;
    if (e < N_EDGES) atomicAdd(&counts[dst[e]], 1);
}

__global__ void k_scan_a(const int* __restrict__ counts, int* __restrict__ excl,
                         int* __restrict__ partials) {
    __shared__ int s[256];
    int i = blockIdx.x * 256 + threadIdx.x;
    int v = (i < N_NODES) ? counts[i] : 0;
    s[threadIdx.x] = v;
    __syncthreads();
    for (int off = 1; off < 256; off <<= 1) {
        int t = (threadIdx.x >= off) ? s[threadIdx.x - off] : 0;
        __syncthreads();
        s[threadIdx.x] += t;
        __syncthreads();
    }
    if (i < N_NODES) excl[i] = s[threadIdx.x] - v;   // exclusive within block
    if (threadIdx.x == 255) partials[blockIdx.x] = s[255];
}

__global__ void k_scan_b(int* __restrict__ partials, int nblk) {
    __shared__ int s[512];
    int t = threadIdx.x;
    int v = (t < nblk) ? partials[t] : 0;
    s[t] = v;
    __syncthreads();
    for (int off = 1; off < 512; off <<= 1) {
        int u = (t >= off) ? s[t - off] : 0;
        __syncthreads();
        s[t] += u;
        __syncthreads();
    }
    if (t < nblk) partials[t] = s[t] - v;            // exclusive
}

__global__ void k_scan_c(int* __restrict__ offsets, int* __restrict__ cursor,
                         const int* __restrict__ partials) {
    int i = blockIdx.x * 256 + threadIdx.x;
    if (i < N_NODES) {
        int v = offsets[i] + partials[blockIdx.x];
        offsets[i] = v;
        cursor[i]  = v;
    }
    if (blockIdx.x == 0 && threadIdx.x == 0) offsets[N_NODES] = N_EDGES;
}

// edge record: x = src*160 + etype*32 (float offset into xrel), y = mask bits
__global__ void k_scatter(const int* __restrict__ src, const int* __restrict__ dst,
                          const int* __restrict__ etype, const float* __restrict__ mask,
                          int* __restrict__ cursor, int2* __restrict__ ebuf) {
    int e = blockIdx.x * blockDim.x + threadIdx.x;
    if (e >= N_EDGES) return;
    int d = dst[e];
    int pos = atomicAdd(&cursor[d], 1);
    int2 pk;
    pk.x = src[e] * 160 + etype[e] * 32;
    pk.y = __float_as_int(mask[e]);
    ebuf[pos] = pk;
}

// ---------------- weight prep: Wbig[d][j], j<160: rel-expanded basis; j>=160: loop ----------------

__global__ void k_prepw(const float* __restrict__ V, const float* __restrict__ comp,
                        const float* __restrict__ loopw, float* __restrict__ Wbig, int D) {
    int idx = blockIdx.x * 256 + threadIdx.x;
    if (idx >= D * 192) return;
    int d = idx / 192, j = idx % 192;
    float v;
    if (j < 160) {
        int r = j >> 5, o = j & 31;
        v = comp[r * 2 + 0] * V[(size_t)(0 * D + d) * 32 + o]
          + comp[r * 2 + 1] * V[(size_t)(1 * D + d) * 32 + o];
    } else {
        v = loopw[d * 32 + (j - 160)];
    }
    Wbig[idx] = v;
}

// ---------------- node transform: tiled GEMM [N,D] @ [D,192] -> xrel[N,160], agg[N,32] ----------------

template <int D>
__global__ __launch_bounds__(256) void k_transform2(
    const float* __restrict__ xin, int xstride,
    const float* __restrict__ Wbig, const float* __restrict__ bias,
    float* __restrict__ xrel, float* __restrict__ agg) {
    __shared__ float xs[64 * 33];     // [node][k], padded
    __shared__ float ws[32 * 192];    // [k][j]
    int t = threadIdx.x;
    int tn = t & 15, to = t >> 4;     // 16 x 16
    int n0 = blockIdx.x * 64;
    float acc[4][12];
#pragma unroll
    for (int a = 0; a < 4; a++)
#pragma unroll
        for (int b = 0; b < 12; b++) acc[a][b] = 0.f;

    for (int kc = 0; kc < D; kc += 32) {
        {   // stage x tile (coalesced 128B rows)
            int col = t & 31, rbase = t >> 5;
#pragma unroll
            for (int i = 0; i < 8; i++) {
                int row = i * 8 + rbase;
                int n = n0 + row;
                float v = 0.f;
                if (n < N_NODES) v = xin[(size_t)n * xstride + kc + col];
                xs[row * 33 + col] = v;
            }
        }
        {   // stage W chunk: flat 6144-float copy via float4
            const float4* srcp = (const float4*)(Wbig + kc * 192);
            float4* dstp = (float4*)ws;
#pragma unroll
            for (int i = 0; i < 6; i++) dstp[t + i * 256] = srcp[t + i * 256];
        }
        __syncthreads();
#pragma unroll 8
        for (int k = 0; k < 32; k++) {
            float xf[4];
#pragma unroll
            for (int ni = 0; ni < 4; ni++) xf[ni] = xs[(tn * 4 + ni) * 33 + k];
            const float4* wr4 = (const float4*)(ws + k * 192 + to * 12);
            float4 w0 = wr4[0], w1 = wr4[1], w2 = wr4[2];
            float wf[12] = {w0.x, w0.y, w0.z, w0.w, w1.x, w1.y, w1.z, w1.w,
                            w2.x, w2.y, w2.z, w2.w};
#pragma unroll
            for (int ni = 0; ni < 4; ni++)
#pragma unroll
                for (int oi = 0; oi < 12; oi++)
                    acc[ni][oi] = fmaf(xf[ni], wf[oi], acc[ni][oi]);
        }
        __syncthreads();
    }
#pragma unroll
    for (int ni = 0; ni < 4; ni++) {
        int n = n0 + tn * 4 + ni;
        if (n >= N_NODES) continue;
#pragma unroll
        for (int oi = 0; oi < 12; oi++) {
            int j = to * 12 + oi;
            float v = acc[ni][oi];
            if (j < 160) xrel[(size_t)n * 160 + j] = v;
            else         agg[(size_t)n * 32 + (j - 160)] = v + bias[j - 160];
        }
    }
}

// ---------------- per-node aggregation: 32 lanes/node, 1 gather (128B) per edge, ILP x4 ----------------

__global__ __launch_bounds__(256) void k_aggregate(
    const int* __restrict__ offsets, const int2* __restrict__ ebuf,
    const float* __restrict__ xrel, const float* __restrict__ agg,
    float* __restrict__ hout, int hstride) {
    int g = threadIdx.x >> 5;      // 8 node-groups per 256-thread block
    int o = threadIdx.x & 31;
    int v = blockIdx.x * 8 + g;
    if (v >= N_NODES) return;
    int s0 = offsets[v], s1 = offsets[v + 1];
    float acc = agg[(size_t)v * 32 + o];
    float a0 = 0.f, a1 = 0.f, a2 = 0.f, a3 = 0.f;
    int e = s0;
    for (; e + 4 <= s1; e += 4) {
        int2 p0 = ebuf[e], p1 = ebuf[e + 1], p2 = ebuf[e + 2], p3 = ebuf[e + 3];
        float x0 = xrel[p0.x + o];
        float x1 = xrel[p1.x + o];
        float x2 = xrel[p2.x + o];
        float x3 = xrel[p3.x + o];
        a0 = fmaf(__int_as_float(p0.y), x0, a0);
        a1 = fmaf(__int_as_float(p1.y), x1, a1);
        a2 = fmaf(__int_as_float(p2.y), x2, a2);
        a3 = fmaf(__int_as_float(p3.y), x3, a3);
    }
    for (; e < s1; e++) {
        int2 pk = ebuf[e];
        a0 = fmaf(__int_as_float(pk.y), xrel[pk.x + o], a0);
    }
    acc += (a0 + a1) + (a2 + a3);
    hout[(size_t)v * hstride + o] = tanhf(acc);
}

// ---------------- MLP head ----------------

__global__ void k_mlp(const float* __restrict__ concat, const int* __restrict__ uidx,
                      const int* __restrict__ iidx,
                      const float* __restrict__ w1, const float* __restrict__ bw1,
                      const float* __restrict__ w2, const float* __restrict__ bw2,
                      float* __restrict__ out) {
    __shared__ float feats[192];
    __shared__ float red[2];
    int p = blockIdx.x;
    int t = threadIdx.x;   // 128 threads
    int u = uidx[p], it = iidx[p];
    for (int k = t; k < 192; k += 128)
        feats[k] = (k < 96) ? concat[(size_t)u * 96 + k] : concat[(size_t)it * 96 + (k - 96)];
    __syncthreads();
    float acc = bw1[t];
    for (int k = 0; k < 192; k++) acc += feats[k] * w1[k * 128 + t];
    float h = fmaxf(acc, 0.f);
    float part = h * w2[t];
    for (int off = 32; off > 0; off >>= 1) part += __shfl_down(part, off, 64);
    if ((t & 63) == 0) red[t >> 6] = part;
    __syncthreads();
    if (t == 0) out[p] = red[0] + red[1] + bw2[0];
}

// ---------------- launch ----------------

extern "C" void kernel_launch(void* const* d_in, const int* in_sizes, int n_in,
                              void* d_out, int out_size, void* d_ws, size_t ws_size,
                              hipStream_t stream) {
    const float* x         = (const float*)d_in[0];
    const float* edge_mask = (const float*)d_in[1];
    const int*   etype     = (const int*)d_in[2];
    const int*   src       = (const int*)d_in[3];
    const int*   dst       = (const int*)d_in[4];
    const int*   users_idx = (const int*)d_in[5];
    const int*   items_idx = (const int*)d_in[6];
    const float* V1        = (const float*)d_in[7];
    const float* comp1     = (const float*)d_in[8];
    const float* loop1     = (const float*)d_in[9];
    const float* b1        = (const float*)d_in[10];
    const float* V2        = (const float*)d_in[11];
    const float* comp2     = (const float*)d_in[12];
    const float* loop2     = (const float*)d_in[13];
    const float* b2        = (const float*)d_in[14];
    const float* V3        = (const float*)d_in[15];
    const float* comp3     = (const float*)d_in[16];
    const float* loop3     = (const float*)d_in[17];
    const float* b3        = (const float*)d_in[18];
    const float* w1        = (const float*)d_in[19];
    const float* bw1       = (const float*)d_in[20];
    const float* w2        = (const float*)d_in[21];
    const float* bw2       = (const float*)d_in[22];
    float* out = (float*)d_out;

    // workspace carve-up (256B aligned)
    uintptr_t w = (uintptr_t)d_ws;
    auto al = [&](size_t bytes) { uintptr_t p = (w + 255) & ~(uintptr_t)255; w = p + bytes; return p; };
    int*   counts   = (int*)al(sizeof(int) * N_NODES);
    int*   offsets  = (int*)al(sizeof(int) * (N_NODES + 1));
    int*   cursor   = (int*)al(sizeof(int) * N_NODES);
    int*   partials = (int*)al(sizeof(int) * 512);
    int2*  ebuf     = (int2*)al(sizeof(int2) * N_EDGES);
    float* Wbig     = (float*)al(sizeof(float) * IN_FEATS * 192);
    float* xrel     = (float*)al(sizeof(float) * (size_t)N_NODES * 160);
    float* agg      = (float*)al(sizeof(float) * (size_t)N_NODES * 32);
    float* concat   = (float*)al(sizeof(float) * (size_t)N_NODES * 96);

    hipMemsetAsync(counts, 0, sizeof(int) * N_NODES, stream);

    k_hist<<<N_EDGES / 256, 256, 0, stream>>>(dst, counts);
    k_scan_a<<<SCAN_BLOCKS, 256, 0, stream>>>(counts, offsets, partials);
    k_scan_b<<<1, 512, 0, stream>>>(partials, SCAN_BLOCKS);
    k_scan_c<<<SCAN_BLOCKS, 256, 0, stream>>>(offsets, cursor, partials);
    k_scatter<<<N_EDGES / 256, 256, 0, stream>>>(src, dst, etype, edge_mask, cursor, ebuf);

    const int tgrid = (N_NODES + 63) / 64;

    // layer 1
    k_prepw<<<(IN_FEATS * 192 + 255) / 256, 256, 0, stream>>>(V1, comp1, loop1, Wbig, IN_FEATS);
    k_transform2<IN_FEATS><<<tgrid, 256, 0, stream>>>(x, IN_FEATS, Wbig, b1, xrel, agg);
    k_aggregate<<<(N_NODES + 7) / 8, 256, 0, stream>>>(offsets, ebuf, xrel, agg, concat + 0, 96);

    // layer 2
    k_prepw<<<(HID * 192 + 255) / 256, 256, 0, stream>>>(V2, comp2, loop2, Wbig, HID);
    k_transform2<HID><<<tgrid, 256, 0, stream>>>(concat + 0, 96, Wbig, b2, xrel, agg);
    k_aggregate<<<(N_NODES + 7) / 8, 256, 0, stream>>>(offsets, ebuf, xrel, agg, concat + 32, 96);

    // layer 3
    k_prepw<<<(HID * 192 + 255) / 256, 256, 0, stream>>>(V3, comp3, loop3, Wbig, HID);
    k_transform2<HID><<<tgrid, 256, 0, stream>>>(concat + 32, 96, Wbig, b3, xrel, agg);
    k_aggregate<<<(N_NODES + 7) / 8, 256, 0, stream>>>(offsets, ebuf, xrel, agg, concat + 64, 96);

    k_mlp<<<N_PAIRS, 128, 0, stream>>>(concat, users_idx, items_idx, w1, bw1, w2, bw2, out);
}

// Round 3
// 617.311 us; speedup vs baseline: 1.3634x; 1.2088x over previous
//
#include <hip/hip_runtime.h>
#include <stdint.h>

#define N_NODES  100000
#define N_EDGES  1600000
#define IN_FEATS 128
#define HID      32
#define N_REL    5
#define N_BASES  2
#define N_PAIRS  4096

#define SCAN_BLOCKS 391   // ceil(100000/256)

__device__ inline unsigned int pack_bf16(float a, float b) {
    unsigned int ua = __float_as_uint(a), ub = __float_as_uint(b);
    ua = (ua + 0x7fffu + ((ua >> 16) & 1u)) >> 16;
    ub = (ub + 0x7fffu + ((ub >> 16) & 1u)) >> 16;
    return ua | (ub << 16);
}

// ---------------- CSR build ----------------

__global__ void k_hist(const int* __restrict__ dst, int* __restrict__ counts) {
    int e = blockIdx.x * blockDim.x + threadIdx.x;
    if (e < N_EDGES) atomicAdd(&counts[dst[e]], 1);
}

__global__ void k_scan_a(const int* __restrict__ counts, int* __restrict__ excl,
                         int* __restrict__ partials) {
    __shared__ int s[256];
    int i = blockIdx.x * 256 + threadIdx.x;
    int v = (i < N_NODES) ? counts[i] : 0;
    s[threadIdx.x] = v;
    __syncthreads();
    for (int off = 1; off < 256; off <<= 1) {
        int t = (threadIdx.x >= off) ? s[threadIdx.x - off] : 0;
        __syncthreads();
        s[threadIdx.x] += t;
        __syncthreads();
    }
    if (i < N_NODES) excl[i] = s[threadIdx.x] - v;   // exclusive within block
    if (threadIdx.x == 255) partials[blockIdx.x] = s[255];
}

__global__ void k_scan_b(int* __restrict__ partials, int nblk) {
    __shared__ int s[512];
    int t = threadIdx.x;
    int v = (t < nblk) ? partials[t] : 0;
    s[t] = v;
    __syncthreads();
    for (int off = 1; off < 512; off <<= 1) {
        int u = (t >= off) ? s[t - off] : 0;
        __syncthreads();
        s[t] += u;
        __syncthreads();
    }
    if (t < nblk) partials[t] = s[t] - v;            // exclusive
}

__global__ void k_scan_c(int* __restrict__ offsets, int* __restrict__ cursor,
                         const int* __restrict__ partials) {
    int i = blockIdx.x * 256 + threadIdx.x;
    if (i < N_NODES) {
        int v = offsets[i] + partials[blockIdx.x];
        offsets[i] = v;
        cursor[i]  = v;
    }
    if (blockIdx.x == 0 && threadIdx.x == 0) offsets[N_NODES] = N_EDGES;
}

// edge record: x = src*80 + etype*16 (uint offset into xrel16), y = mask bits
__global__ void k_scatter(const int* __restrict__ src, const int* __restrict__ dst,
                          const int* __restrict__ etype, const float* __restrict__ mask,
                          int* __restrict__ cursor, int2* __restrict__ ebuf) {
    int e = blockIdx.x * blockDim.x + threadIdx.x;
    if (e >= N_EDGES) return;
    int d = dst[e];
    int pos = atomicAdd(&cursor[d], 1);
    int2 pk;
    pk.x = src[e] * 80 + etype[e] * 16;
    pk.y = __float_as_int(mask[e]);
    ebuf[pos] = pk;
}

// ---------------- weight prep: Wbig[d][j], j<160: rel-expanded basis; j>=160: loop ----------------

__global__ void k_prepw(const float* __restrict__ V, const float* __restrict__ comp,
                        const float* __restrict__ loopw, float* __restrict__ Wbig, int D) {
    int idx = blockIdx.x * 256 + threadIdx.x;
    if (idx >= D * 192) return;
    int d = idx / 192, j = idx % 192;
    float v;
    if (j < 160) {
        int r = j >> 5, o = j & 31;
        v = comp[r * 2 + 0] * V[(size_t)(0 * D + d) * 32 + o]
          + comp[r * 2 + 1] * V[(size_t)(1 * D + d) * 32 + o];
    } else {
        v = loopw[d * 32 + (j - 160)];
    }
    Wbig[idx] = v;
}

// ---------------- node transform: tiled GEMM [N,D] @ [D,192] -> xrel16[N,80] (bf16x2), agg[N,32] ----------------

template <int D>
__global__ __launch_bounds__(256) void k_transform2(
    const float* __restrict__ xin, int xstride,
    const float* __restrict__ Wbig, const float* __restrict__ bias,
    unsigned int* __restrict__ xrel16, float* __restrict__ agg) {
    __shared__ float xs[64 * 33];     // [node][k], padded
    __shared__ float ws[32 * 192];    // [k][j]
    int t = threadIdx.x;
    int tn = t & 15, to = t >> 4;     // 16 x 16
    int n0 = blockIdx.x * 64;
    float acc[4][12];
#pragma unroll
    for (int a = 0; a < 4; a++)
#pragma unroll
        for (int b = 0; b < 12; b++) acc[a][b] = 0.f;

    for (int kc = 0; kc < D; kc += 32) {
        {   // stage x tile (coalesced 128B rows)
            int col = t & 31, rbase = t >> 5;
#pragma unroll
            for (int i = 0; i < 8; i++) {
                int row = i * 8 + rbase;
                int n = n0 + row;
                float v = 0.f;
                if (n < N_NODES) v = xin[(size_t)n * xstride + kc + col];
                xs[row * 33 + col] = v;
            }
        }
        {   // stage W chunk: flat 6144-float copy via float4
            const float4* srcp = (const float4*)(Wbig + kc * 192);
            float4* dstp = (float4*)ws;
#pragma unroll
            for (int i = 0; i < 6; i++) dstp[t + i * 256] = srcp[t + i * 256];
        }
        __syncthreads();
#pragma unroll 8
        for (int k = 0; k < 32; k++) {
            float xf[4];
#pragma unroll
            for (int ni = 0; ni < 4; ni++) xf[ni] = xs[(tn * 4 + ni) * 33 + k];
            const float4* wr4 = (const float4*)(ws + k * 192 + to * 12);
            float4 w0 = wr4[0], w1 = wr4[1], w2 = wr4[2];
            float wf[12] = {w0.x, w0.y, w0.z, w0.w, w1.x, w1.y, w1.z, w1.w,
                            w2.x, w2.y, w2.z, w2.w};
#pragma unroll
            for (int ni = 0; ni < 4; ni++)
#pragma unroll
                for (int oi = 0; oi < 12; oi++)
                    acc[ni][oi] = fmaf(xf[ni], wf[oi], acc[ni][oi]);
        }
        __syncthreads();
    }
#pragma unroll
    for (int ni = 0; ni < 4; ni++) {
        int n = n0 + tn * 4 + ni;
        if (n >= N_NODES) continue;
#pragma unroll
        for (int oi = 0; oi < 12; oi += 2) {
            int j = to * 12 + oi;
            if (j < 160) {
                xrel16[(size_t)n * 80 + (j >> 1)] = pack_bf16(acc[ni][oi], acc[ni][oi + 1]);
            } else {
                agg[(size_t)n * 32 + (j - 160)]     = acc[ni][oi]     + bias[j - 160];
                agg[(size_t)n * 32 + (j - 160) + 1] = acc[ni][oi + 1] + bias[j - 159];
            }
        }
    }
}

// ---------------- per-node aggregation: 16 lanes/node, 2 outputs/lane, 8 gathers in flight ----------------

__global__ __launch_bounds__(256) void k_aggregate(
    const int* __restrict__ offsets, const int2* __restrict__ ebuf,
    const unsigned int* __restrict__ xrel16, const float* __restrict__ agg,
    float* __restrict__ hout, int hstride) {
    int g = threadIdx.x >> 4;      // 16 node-groups per 256-thread block
    int o = threadIdx.x & 15;      // uint index -> outputs 2o, 2o+1
    int v = blockIdx.x * 16 + g;
    if (v >= N_NODES) return;
    int s0 = offsets[v], s1 = offsets[v + 1];
    float acc0 = agg[(size_t)v * 32 + 2 * o];
    float acc1 = agg[(size_t)v * 32 + 2 * o + 1];
    int last = s1 - 1;
    for (int e = s0; e < s1; e += 8) {
        int addr[8];
        float m[8];
#pragma unroll
        for (int i = 0; i < 8; i++) {
            int ei = e + i;
            int ec = (ei <= last) ? ei : last;
            int2 pk = ebuf[ec];
            addr[i] = pk.x;
            m[i] = (ei <= last) ? __int_as_float(pk.y) : 0.f;
        }
        unsigned int xw[8];
#pragma unroll
        for (int i = 0; i < 8; i++) xw[i] = xrel16[(unsigned)addr[i] + o];
#pragma unroll
        for (int i = 0; i < 8; i++) {
            float lo = __uint_as_float(xw[i] << 16);
            float hi = __uint_as_float(xw[i] & 0xffff0000u);
            acc0 = fmaf(m[i], lo, acc0);
            acc1 = fmaf(m[i], hi, acc1);
        }
    }
    hout[(size_t)v * hstride + 2 * o]     = tanhf(acc0);
    hout[(size_t)v * hstride + 2 * o + 1] = tanhf(acc1);
}

// ---------------- MLP head ----------------

__global__ void k_mlp(const float* __restrict__ concat, const int* __restrict__ uidx,
                      const int* __restrict__ iidx,
                      const float* __restrict__ w1, const float* __restrict__ bw1,
                      const float* __restrict__ w2, const float* __restrict__ bw2,
                      float* __restrict__ out) {
    __shared__ float feats[192];
    __shared__ float red[2];
    int p = blockIdx.x;
    int t = threadIdx.x;   // 128 threads
    int u = uidx[p], it = iidx[p];
    for (int k = t; k < 192; k += 128)
        feats[k] = (k < 96) ? concat[(size_t)u * 96 + k] : concat[(size_t)it * 96 + (k - 96)];
    __syncthreads();
    float acc = bw1[t];
    for (int k = 0; k < 192; k++) acc += feats[k] * w1[k * 128 + t];
    float h = fmaxf(acc, 0.f);
    float part = h * w2[t];
    for (int off = 32; off > 0; off >>= 1) part += __shfl_down(part, off, 64);
    if ((t & 63) == 0) red[t >> 6] = part;
    __syncthreads();
    if (t == 0) out[p] = red[0] + red[1] + bw2[0];
}

// ---------------- launch ----------------

extern "C" void kernel_launch(void* const* d_in, const int* in_sizes, int n_in,
                              void* d_out, int out_size, void* d_ws, size_t ws_size,
                              hipStream_t stream) {
    const float* x         = (const float*)d_in[0];
    const float* edge_mask = (const float*)d_in[1];
    const int*   etype     = (const int*)d_in[2];
    const int*   src       = (const int*)d_in[3];
    const int*   dst       = (const int*)d_in[4];
    const int*   users_idx = (const int*)d_in[5];
    const int*   items_idx = (const int*)d_in[6];
    const float* V1        = (const float*)d_in[7];
    const float* comp1     = (const float*)d_in[8];
    const float* loop1     = (const float*)d_in[9];
    const float* b1        = (const float*)d_in[10];
    const float* V2        = (const float*)d_in[11];
    const float* comp2     = (const float*)d_in[12];
    const float* loop2     = (const float*)d_in[13];
    const float* b2        = (const float*)d_in[14];
    const float* V3        = (const float*)d_in[15];
    const float* comp3     = (const float*)d_in[16];
    const float* loop3     = (const float*)d_in[17];
    const float* b3        = (const float*)d_in[18];
    const float* w1        = (const float*)d_in[19];
    const float* bw1       = (const float*)d_in[20];
    const float* w2        = (const float*)d_in[21];
    const float* bw2       = (const float*)d_in[22];
    float* out = (float*)d_out;

    // workspace carve-up (256B aligned)
    uintptr_t w = (uintptr_t)d_ws;
    auto al = [&](size_t bytes) { uintptr_t p = (w + 255) & ~(uintptr_t)255; w = p + bytes; return p; };
    int*   counts   = (int*)al(sizeof(int) * N_NODES);
    int*   offsets  = (int*)al(sizeof(int) * (N_NODES + 1));
    int*   cursor   = (int*)al(sizeof(int) * N_NODES);
    int*   partials = (int*)al(sizeof(int) * 512);
    int2*  ebuf     = (int2*)al(sizeof(int2) * N_EDGES);
    float* Wbig     = (float*)al(sizeof(float) * IN_FEATS * 192);
    unsigned int* xrel16 = (unsigned int*)al(sizeof(unsigned int) * (size_t)N_NODES * 80);
    float* agg      = (float*)al(sizeof(float) * (size_t)N_NODES * 32);
    float* concat   = (float*)al(sizeof(float) * (size_t)N_NODES * 96);

    hipMemsetAsync(counts, 0, sizeof(int) * N_NODES, stream);

    k_hist<<<N_EDGES / 256, 256, 0, stream>>>(dst, counts);
    k_scan_a<<<SCAN_BLOCKS, 256, 0, stream>>>(counts, offsets, partials);
    k_scan_b<<<1, 512, 0, stream>>>(partials, SCAN_BLOCKS);
    k_scan_c<<<SCAN_BLOCKS, 256, 0, stream>>>(offsets, cursor, partials);
    k_scatter<<<N_EDGES / 256, 256, 0, stream>>>(src, dst, etype, edge_mask, cursor, ebuf);

    const int tgrid = (N_NODES + 63) / 64;
    const int agrid = (N_NODES + 15) / 16;

    // layer 1
    k_prepw<<<(IN_FEATS * 192 + 255) / 256, 256, 0, stream>>>(V1, comp1, loop1, Wbig, IN_FEATS);
    k_transform2<IN_FEATS><<<tgrid, 256, 0, stream>>>(x, IN_FEATS, Wbig, b1, xrel16, agg);
    k_aggregate<<<agrid, 256, 0, stream>>>(offsets, ebuf, xrel16, agg, concat + 0, 96);

    // layer 2
    k_prepw<<<(HID * 192 + 255) / 256, 256, 0, stream>>>(V2, comp2, loop2, Wbig, HID);
    k_transform2<HID><<<tgrid, 256, 0, stream>>>(concat + 0, 96, Wbig, b2, xrel16, agg);
    k_aggregate<<<agrid, 256, 0, stream>>>(offsets, ebuf, xrel16, agg, concat + 32, 96);

    // layer 3
    k_prepw<<<(HID * 192 + 255) / 256, 256, 0, stream>>>(V3, comp3, loop3, Wbig, HID);
    k_transform2<HID><<<tgrid, 256, 0, stream>>>(concat + 32, 96, Wbig, b3, xrel16, agg);
    k_aggregate<<<agrid, 256, 0, stream>>>(offsets, ebuf, xrel16, agg, concat + 64, 96);

    k_mlp<<<N_PAIRS, 128, 0, stream>>>(concat, users_idx, items_idx, w1, bw1, w2, bw2, out);
}